// Round 10
// baseline (352.404 us; speedup 1.0000x reference)
//
#include <hip/hip_runtime.h>
#include <hip/hip_bf16.h>
#include <math.h>

#define TT 2048
#define NE 256
#define NHEAD 16

typedef __attribute__((ext_vector_type(8))) short bf16x8;
typedef __attribute__((ext_vector_type(4))) float f32x4;
typedef __attribute__((ext_vector_type(16))) float f32x16;
typedef unsigned short ushort;
typedef __attribute__((ext_vector_type(8))) unsigned short us8;

__device__ __forceinline__ short f2bf(float x) {  // RNE (weights only)
  __hip_bfloat16 h = __float2bfloat16(x);
  return *reinterpret_cast<short*>(&h);
}
__device__ __forceinline__ ushort f2bf_fast(float x) {  // round-half-up, 2 ops
  return (ushort)((__float_as_uint(x) + 0x8000u) >> 16);
}
__device__ __forceinline__ unsigned pack2bf_fast(float a, float b) {  // 3 ops
  unsigned ua = __float_as_uint(a) + 0x8000u;
  unsigned ub = __float_as_uint(b) + 0x8000u;
  return __builtin_amdgcn_perm(ub, ua, 0x07060302u);
}
__device__ __forceinline__ float bf2f(ushort u) {
  unsigned v = ((unsigned)u) << 16;
  return __uint_as_float(v);
}

// ---------------- 1. logmap -> xh bf16 + x bf16 + f32 imp scores ----------------
__global__ __launch_bounds__(256) void logmap_kernel(const float* __restrict__ x,
                                                     const float* __restrict__ W_imp,
                                                     const float* __restrict__ b_imp,
                                                     ushort* __restrict__ xhb,
                                                     ushort* __restrict__ xbf,
                                                     float* __restrict__ scores) {
  __shared__ float red[20];
  int row = blockIdx.x, tid = threadIdx.x;
  int t = row & (TT - 1);
  float uv = x[row * NE + tid];
  float rv = (t == 0) ? 0.f : x[row * NE - NE + tid];
  xbf[row * NE + tid] = f2bf_fast(uv);
  float a = rv * rv, bq = uv * uv, c2 = -rv * uv, d4 = uv * W_imp[tid];
#pragma unroll
  for (int off = 32; off > 0; off >>= 1) {
    a += __shfl_down(a, off, 64);
    bq += __shfl_down(bq, off, 64);
    c2 += __shfl_down(c2, off, 64);
    d4 += __shfl_down(d4, off, 64);
  }
  if ((tid & 63) == 0) {
    int w = tid >> 6;
    red[w] = a; red[4 + w] = bq; red[8 + w] = c2; red[16 + w] = d4;
  }
  __syncthreads();
  float xn2 = red[0] + red[1] + red[2] + red[3];
  float un2 = red[4] + red[5] + red[6] + red[7];
  float ip  = red[8] + red[9] + red[10] + red[11];
  if (tid == 0) scores[row] = red[16] + red[17] + red[18] + red[19] + b_imp[0];
  float den = 1.f + 2.f * ip + xn2 * un2;
  float mob = ((1.f + 2.f * ip + un2) * (-rv) + (1.f - xn2) * uv) / den;
  float m2 = mob * mob;
#pragma unroll
  for (int off = 32; off > 0; off >>= 1) m2 += __shfl_down(m2, off, 64);
  if ((tid & 63) == 0) red[12 + (tid >> 6)] = m2;
  __syncthreads();
  float an2 = red[12] + red[13] + red[14] + red[15];
  float an = sqrtf(an2);
  float cf = 1.f + xn2;
  float arg = fminf(sqrtf(an), 0.999f);
  xhb[row * NE + tid] = f2bf_fast(cf * atanhf(arg) * mob / an);
}

// ---------------- merged weight convert ----------------
__global__ __launch_bounds__(256) void wtconv_all_kernel(
    const float* __restrict__ W_dqn, const float* __restrict__ W_dqr,
    const float* __restrict__ W_dkn, const float* __restrict__ W_dv,
    const float* __restrict__ W_selk, const float* __restrict__ W_selv,
    const float* __restrict__ W_wink, const float* __restrict__ W_winv,
    const float* __restrict__ W_proj, const float* __restrict__ W_cq,
    const float* __restrict__ W_ckv, const float* __restrict__ W_kr,
    const float* __restrict__ W_gate, const float* __restrict__ W_imp,
    ushort* __restrict__ Wt_q, ushort* __restrict__ Wt_kv,
    ushort* __restrict__ Wt_sel, ushort* __restrict__ Wt_win,
    ushort* __restrict__ Wt_proj, ushort* __restrict__ Wt_cq,
    ushort* __restrict__ Wt_nkv) {
  int i = blockIdx.x * 256 + threadIdx.x;
  // 1/sqrt(96) * log2(e): scores come out in log2 domain -> exp2 softmax
  const float scale = 0.14724456f;
  if (i < 147456) {  // Wt_q [1536 n][96 k]
    int k = i / 1536, n = i - k * 1536;
    float v = (n < 512) ? W_dqn[(size_t)k * 512 + n] : W_dqr[(size_t)k * 1024 + (n - 512)];
    Wt_q[(size_t)n * 96 + k] = (ushort)f2bf(v * scale);
  } else if (i < 180224) {  // Wt_kv [1024 n][32 k]
    int j = i - 147456;
    int k = j >> 10, n = j & 1023;
    float v = (n < 512) ? W_dkn[(size_t)k * 512 + n] : W_dv[(size_t)k * 512 + (n - 512)];
    Wt_kv[(size_t)n * 32 + k] = (ushort)f2bf(v);
  } else if (i < 704512) {  // Wt_sel [2048 n][256 k]
    int j = i - 180224;
    int k = j >> 11, n = j & 2047;
    float v = (n < 1536) ? W_selk[(size_t)k * 1536 + n] : W_selv[(size_t)k * 512 + (n - 1536)];
    Wt_sel[(size_t)n * 256 + k] = (ushort)f2bf(v);
  } else if (i < 1228800) {  // Wt_win [2048 n][256 k]
    int j = i - 704512;
    int k = j >> 11, n = j & 2047;
    float v = (n < 1536) ? W_wink[(size_t)k * 1536 + n] : W_winv[(size_t)k * 512 + (n - 1536)];
    Wt_win[(size_t)n * 256 + k] = (ushort)f2bf(v);
  } else if (i < 1359872) {  // Wt_proj [256 n][512 k]
    int j = i - 1228800;
    int k = j >> 8, n = j & 255;
    Wt_proj[(size_t)n * 512 + k] = (ushort)f2bf(W_proj[(size_t)k * 256 + n]);
  } else if (i < 1392640) {  // Wt_cq [128 n][256 k]
    int j = i - 1359872;
    int k = j >> 7, n = j & 127;
    float v = (n < 96) ? W_cq[(size_t)k * 96 + n] : 0.f;
    Wt_cq[(size_t)n * 256 + k] = (ushort)f2bf(v);
  } else if (i < 1425408) {  // Wt_nkv [128 n][256 k]: [ckv32|kr64|gate3|pad]
    int j = i - 1392640;
    int k = j >> 7, n = j & 127;
    float v;
    if (n < 32) v = W_ckv[(size_t)k * 32 + n];
    else if (n < 96) v = W_kr[(size_t)k * 64 + (n - 32)];
    else if (n < 99) v = W_gate[(size_t)k * 3 + (n - 96)];
    else v = 0.f;
    Wt_nkv[(size_t)n * 256 + k] = (ushort)f2bf(v);
  }
}

// ---------------- multi-mode bf16 MFMA GEMM ----------------
__global__ __launch_bounds__(256) void gemm_kernel(
    int mode,
    const ushort* __restrict__ xhb, const ushort* __restrict__ Wt_cq, float* __restrict__ nqraw,
    const ushort* __restrict__ xbf, const ushort* __restrict__ Wt_nkv, float* __restrict__ nkvraw,
    const ushort* __restrict__ nqb, const ushort* __restrict__ Wt_q, ushort* __restrict__ qbf,
    const ushort* __restrict__ nkvb, const ushort* __restrict__ Wt_kv, ushort* __restrict__ kvtmp,
    const ushort* __restrict__ Wt_win, ushort* __restrict__ wintmp,
    const ushort* __restrict__ Wt_sel, ushort* __restrict__ seltmp,
    const int* __restrict__ selidx,
    const ushort* __restrict__ att0, const ushort* __restrict__ att1,
    const ushort* __restrict__ att2, const ushort* __restrict__ Wt_proj,
    float* __restrict__ outF,
    const float* __restrict__ cosp, const float* __restrict__ sinp) {
  __shared__ __align__(16) short As[128 * 40];
  __shared__ __align__(16) short Bs[128 * 40];
  int tid = threadIdx.x;
  int wv = tid >> 6, lane = tid & 63;
  int l15 = lane & 15, quad = lane >> 4;
  int wm = wv >> 1, wn = wv & 1;

  const ushort* A = nullptr;
  const ushort* Bt = nullptr;
  void* Out = nullptr;
  int K, ldo, obf16 = 1, rope = 0, gather = 0, sum3 = 0;
  int m0 = blockIdx.x * 128, n0 = blockIdx.y * 128;
  if (mode == 0) {
    K = 256; ldo = 128; obf16 = 0;
    if (blockIdx.z == 0) { A = xhb; Bt = Wt_cq; Out = nqraw; }
    else { A = xbf; Bt = Wt_nkv; Out = nkvraw; }
  } else if (mode == 1) {
    if (blockIdx.y < 12) {
      A = nqb; Bt = Wt_q; Out = qbf; K = 96; ldo = 1536;
      rope = (blockIdx.y >= 4);
    } else {
      A = nkvb; Bt = Wt_kv; Out = kvtmp; K = 32; ldo = 1024;
      n0 = (blockIdx.y - 12) * 128;
    }
  } else if (mode == 2) {
    K = 256; ldo = 2048;
    if (blockIdx.x < 32) { A = xbf; Bt = Wt_win; Out = wintmp; }
    else { A = xbf; Bt = Wt_sel; Out = seltmp; gather = 1; m0 = (blockIdx.x - 32) * 128; }
  } else {
    K = 512; ldo = 256; obf16 = 0; sum3 = 1; Bt = Wt_proj; Out = outF;
  }

  int r = tid >> 1, seg = tid & 1;
  int arow = m0 + r;
  if (gather) arow = ((arow >> 9) * TT) + selidx[m0 + r];
  const ushort* ga = A + (size_t)arow * K + seg * 16;
  const ushort* gb = Bt + (size_t)(n0 + r) * K + seg * 16;

  auto loadA = [&](int kk, us8& a0, us8& a1) {
    if (sum3) {
      size_t base = (size_t)arow * 512 + seg * 16 + kk * 32;
      us8 p0 = *(const us8*)(att0 + base), p1 = *(const us8*)(att0 + base + 8);
      us8 q0 = *(const us8*)(att1 + base), q1 = *(const us8*)(att1 + base + 8);
      us8 r0 = *(const us8*)(att2 + base), r1 = *(const us8*)(att2 + base + 8);
#pragma unroll
      for (int e = 0; e < 8; ++e) {
        a0[e] = f2bf_fast(bf2f(p0[e]) + bf2f(q0[e]) + bf2f(r0[e]));
        a1[e] = f2bf_fast(bf2f(p1[e]) + bf2f(q1[e]) + bf2f(r1[e]));
      }
    } else {
      a0 = *(const us8*)(ga + kk * 32);
      a1 = *(const us8*)(ga + kk * 32 + 8);
    }
  };

  f32x4 acc[4][4];
#pragma unroll
  for (int i = 0; i < 4; ++i)
#pragma unroll
    for (int j = 0; j < 4; ++j) acc[i][j] = (f32x4){0.f, 0.f, 0.f, 0.f};

  int nk = K >> 5;
  us8 apre0, apre1, bpre0, bpre1;
  loadA(0, apre0, apre1);
  bpre0 = *(const us8*)gb;
  bpre1 = *(const us8*)(gb + 8);
  for (int kk = 0; kk < nk; ++kk) {
    __syncthreads();
    *(us8*)(As + r * 40 + seg * 16) = apre0;
    *(us8*)(As + r * 40 + seg * 16 + 8) = apre1;
    *(us8*)(Bs + r * 40 + seg * 16) = bpre0;
    *(us8*)(Bs + r * 40 + seg * 16 + 8) = bpre1;
    __syncthreads();
    if (kk + 1 < nk) {
      loadA(kk + 1, apre0, apre1);
      bpre0 = *(const us8*)(gb + (kk + 1) * 32);
      bpre1 = *(const us8*)(gb + (kk + 1) * 32 + 8);
    }
    bf16x8 af[4], bf[4];
#pragma unroll
    for (int mf = 0; mf < 4; ++mf)
      af[mf] = *(const bf16x8*)(As + (wm * 64 + mf * 16 + l15) * 40 + quad * 8);
#pragma unroll
    for (int nf = 0; nf < 4; ++nf)
      bf[nf] = *(const bf16x8*)(Bs + (wn * 64 + nf * 16 + l15) * 40 + quad * 8);
#pragma unroll
    for (int mf = 0; mf < 4; ++mf)
#pragma unroll
      for (int nf = 0; nf < 4; ++nf)
        acc[mf][nf] = __builtin_amdgcn_mfma_f32_16x16x32_bf16(af[mf], bf[nf], acc[mf][nf], 0, 0, 0);
  }

  if (rope) {
#pragma unroll
    for (int mf = 0; mf < 4; ++mf) {
#pragma unroll
      for (int nf = 0; nf < 2; ++nf) {
        int dd = nf * 16 + l15;
#pragma unroll
        for (int reg = 0; reg < 4; ++reg) {
          int row = m0 + wm * 64 + mf * 16 + quad * 4 + reg;
          int t = row & (TT - 1);
          float c = cosp[t * 32 + dd], s = sinp[t * 32 + dd];
          float xr = acc[mf][nf][reg], xi = acc[mf][nf + 2][reg];
          int col = n0 + wn * 64 + nf * 16 + l15;
          size_t oi = (size_t)row * ldo + col;
          ((ushort*)Out)[oi] = f2bf_fast(xr * c - xi * s);
          ((ushort*)Out)[oi + 32] = f2bf_fast(xr * s + xi * c);
        }
      }
    }
    return;
  }
#pragma unroll
  for (int mf = 0; mf < 4; ++mf) {
#pragma unroll
    for (int nf = 0; nf < 4; ++nf) {
#pragma unroll
      for (int reg = 0; reg < 4; ++reg) {
        int row = m0 + wm * 64 + mf * 16 + quad * 4 + reg;
        int col = n0 + wn * 64 + nf * 16 + l15;
        size_t oi = (size_t)row * ldo + col;
        float v = acc[mf][nf][reg];
        if (obf16) ((ushort*)Out)[oi] = f2bf_fast(v);
        else ((float*)Out)[oi] = v;
      }
    }
  }
}

// ---------------- merged norm/postproc ----------------
__global__ __launch_bounds__(128) void norm_kernel(const float* __restrict__ nkvraw,
                                                   const float* __restrict__ nqraw,
                                                   const float* __restrict__ kvnw,
                                                   const float* __restrict__ qnw,
                                                   const float* __restrict__ cos_t,
                                                   const float* __restrict__ sin_t,
                                                   ushort* __restrict__ nkvb,
                                                   ushort* __restrict__ krbf,
                                                   ushort* __restrict__ nqb) {
  int tid = threadIdx.x;
  if (blockIdx.x < 4096) {
    int row = blockIdx.x;
    int t = row & (TT - 1);
    if (tid < 32) {
      float v = nkvraw[(size_t)row * 128 + tid];
      float ss = v * v;
#pragma unroll
      for (int off = 16; off > 0; off >>= 1) ss += __shfl_xor(ss, off, 32);
      nkvb[(size_t)row * 32 + tid] = f2bf_fast(v * rsqrtf(ss / 32.f + 1e-6f) * kvnw[tid]);
    } else if (tid < 64) {
      int dd = tid - 32;
      float xr = nkvraw[(size_t)row * 128 + 32 + dd];
      float xi = nkvraw[(size_t)row * 128 + 64 + dd];
      float c = cos_t[t * 32 + dd], s = sin_t[t * 32 + dd];
      krbf[(size_t)row * 64 + dd] = f2bf_fast(xr * c - xi * s);
      krbf[(size_t)row * 64 + dd + 32] = f2bf_fast(xr * s + xi * c);
    }
  } else {
    int row = blockIdx.x - 4096;
    __shared__ float red2[2];
    float v = (tid < 96) ? nqraw[(size_t)row * 128 + tid] : 0.f;
    float p = v * v;
#pragma unroll
    for (int off = 32; off > 0; off >>= 1) p += __shfl_down(p, off, 64);
    if ((tid & 63) == 0) red2[tid >> 6] = p;
    __syncthreads();
    float ss = red2[0] + red2[1];
    float sc = rsqrtf(ss / 96.f + 1e-6f);
    if (tid < 96) nqb[(size_t)row * 96 + tid] = f2bf_fast(v * sc * qnw[tid]);
  }
}

// ---------------- top-k stage 1: ranks -> flags ----------------
__global__ __launch_bounds__(1024) void topk_rank_kernel(const float* __restrict__ scores,
                                                         int* __restrict__ flags) {
  int b = blockIdx.y, blk = blockIdx.x;
  int tid = threadIdx.x;
  __shared__ unsigned sk[TT];
#pragma unroll
  for (int e = 0; e < 2; ++e) {
    int i = tid + e * 1024;
    float s = scores[b * TT + i];
    unsigned u = __float_as_uint(s);
    u = (u & 0x80000000u) ? ~u : (u | 0x80000000u);
    sk[i] = u;
  }
  __syncthreads();
  int e = blk * 64 + (tid >> 4);
  int sub = tid & 15;
  unsigned u = sk[e];
  int r = 0;
  int j0 = sub * 128;
#pragma unroll 8
  for (int j = j0; j < j0 + 128; ++j) {
    unsigned v = sk[j];
    r += (int)((v > u) || (v == u && j < e));
  }
#pragma unroll
  for (int off = 8; off > 0; off >>= 1) r += __shfl_down(r, off, 16);
  if (sub == 0) flags[b * TT + e] = (r < 512) ? 1 : 0;
}

// ---------------- top-k stage 2: scan + scatter + gate finalize ----------------
__global__ __launch_bounds__(1024) void topk_scan_kernel(const int* __restrict__ flags,
                                                         int* __restrict__ selidx,
                                                         const float* __restrict__ nkvraw,
                                                         const float* __restrict__ b_gate,
                                                         float* __restrict__ bw) {
  int b = blockIdx.x, tid = threadIdx.x;
  __shared__ int pre[TT];
  __shared__ float gred[3][16];
  int f0 = flags[b * TT + tid], f1 = flags[b * TT + tid + 1024];
  pre[tid] = f0;
  pre[tid + 1024] = f1;
  __syncthreads();
  for (int off = 1; off < TT; off <<= 1) {
    int a0 = (tid >= off) ? pre[tid - off] : 0;
    int a1 = (tid + 1024 >= off) ? pre[tid + 1024 - off] : 0;
    __syncthreads();
    pre[tid] += a0;
    pre[tid + 1024] += a1;
    __syncthreads();
  }
  if (f0) selidx[b * 512 + pre[tid] - 1] = tid;
  if (f1) selidx[b * 512 + pre[tid + 1024] - 1] = tid + 1024;
  float g0 = 0, g1 = 0, g2 = 0;
  for (int r = tid; r < TT; r += 1024) {
    const float* p = nkvraw + (size_t)(b * TT + r) * 128 + 96;
    g0 += p[0]; g1 += p[1]; g2 += p[2];
  }
#pragma unroll
  for (int off = 32; off > 0; off >>= 1) {
    g0 += __shfl_down(g0, off, 64);
    g1 += __shfl_down(g1, off, 64);
    g2 += __shfl_down(g2, off, 64);
  }
  if ((tid & 63) == 0) {
    int w = tid >> 6;
    gred[0][w] = g0; gred[1][w] = g1; gred[2][w] = g2;
  }
  __syncthreads();
  if (tid == 0) {
    float v[3], mx = -INFINITY;
    for (int j = 0; j < 3; ++j) {
      float s = 0;
      for (int w = 0; w < 16; ++w) s += gred[j][w];
      v[j] = s / (float)TT + b_gate[j];
      mx = fmaxf(mx, v[j]);
    }
    float sum = 0.f;
    for (int j = 0; j < 3; ++j) { v[j] = expf(v[j] - mx); sum += v[j]; }
    for (int j = 0; j < 3; ++j) bw[b * 3 + j] = v[j] / sum;
  }
}

// ---------------- flash attention: source-split, register Q/K, shuffle-P ----------------
// Scores arrive in log2 domain (scale folded into Wt_q) -> exp2 softmax.
template <int SPLIT>
__device__ __forceinline__ void flash_src(
    const ushort* __restrict__ qbf, const ushort* __restrict__ kb1, size_t krs1,
    const ushort* __restrict__ kb2, size_t krs2,
    const ushort* __restrict__ vb, size_t vrs,
    int Tk, int causal, int qtile, int b, int h, float wgt,
    ushort* __restrict__ outbuf, short* VtsAll, float* Ls) {
  int tid = threadIdx.x;
  int wv = tid >> 6, lane = tid & 63;
  int l31 = lane & 31, half = lane >> 5;
  int qrow0 = qtile * 128;
  size_t bTk = (size_t)b * Tk;

  // Q fragments in registers (reused across all K-tiles)
  bf16x8 qfr[6];
  {
    const ushort* qrow = qbf + (size_t)(b * TT + qrow0 + wv * 32 + l31) * 1536;
#pragma unroll
    for (int ks = 0; ks < 6; ++ks) {
      int dp = ks * 16 + half * 8;
      int col = (dp < 32) ? (h * 32 + dp) : (512 + h * 64 + (dp - 32));
      qfr[ks] = *(const bf16x8*)(qrow + col);
    }
  }
  // K base pointers with per-lane part hoisted out of the loop
  const ushort* kptr[6];
#pragma unroll
  for (int ks = 0; ks < 6; ++ks) {
    int dp = ks * 16 + half * 8;
    kptr[ks] = (dp < SPLIT) ? kb1 + (bTk + l31) * krs1 + dp
                            : kb2 + (bTk + l31) * krs2 + (dp - SPLIT);
  }
  // V pointers likewise
  const ushort* vptrA[2];
  const ushort* vptrB[2];
#pragma unroll
  for (int c = 0; c < 2; ++c) {
    int i = c * 256 + tid;
    int d0 = (i & 15) * 2, kjp = (i >> 4) * 2;
    vptrA[c] = vb + (bTk + kjp) * vrs + d0;
    vptrB[c] = vptrA[c] + vrs;
  }

  f32x16 of;
#pragma unroll
  for (int r = 0; r < 16; ++r) of[r] = 0.f;
  float lsum = 0.f;

  ushort2 vpa[2], vpb[2];
  auto vprefetch = [&](int kt) {
    size_t o = (size_t)(kt * 64) * vrs;
#pragma unroll
    for (int c = 0; c < 2; ++c) {
      vpa[c] = *(const ushort2*)(vptrA[c] + o);
      vpb[c] = *(const ushort2*)(vptrB[c] + o);
    }
  };

  int nkt = causal ? (2 * qtile + 2) : (Tk >> 6);
  int qg = qrow0 + wv * 32 + l31;
  int qwave0 = qrow0 + wv * 32;  // wave-uniform
  vprefetch(0);
  for (int kt = 0; kt < nkt; ++kt) {
    short* Vts = VtsAll + (kt & 1) * (32 * 72);
#pragma unroll
    for (int c = 0; c < 2; ++c) {
      int i = c * 256 + tid;
      int d0 = (i & 15) * 2, kjp = (i >> 4) * 2;
      *(unsigned*)(Vts + (d0 + 0) * 72 + kjp) =
          (unsigned)vpa[c].x | ((unsigned)vpb[c].x << 16);
      *(unsigned*)(Vts + (d0 + 1) * 72 + kjp) =
          (unsigned)vpa[c].y | ((unsigned)vpb[c].y << 16);
    }
    __syncthreads();
    if (kt + 1 < nkt) vprefetch(kt + 1);

#pragma unroll
    for (int kb = 0; kb < 2; ++kb) {
      int key0 = kt * 64 + kb * 32;
      bf16x8 kfr[6];
#pragma unroll
      for (int ks = 0; ks < 6; ++ks) {
        int dp = ks * 16 + half * 8;
        size_t krs = (dp < SPLIT) ? krs1 : krs2;  // compile-time select
        kfr[ks] = *(const bf16x8*)(kptr[ks] + (size_t)key0 * krs);
      }
      f32x16 sfT;
#pragma unroll
      for (int r = 0; r < 16; ++r) sfT[r] = 0.f;
#pragma unroll
      for (int ks = 0; ks < 6; ++ks)
        sfT = __builtin_amdgcn_mfma_f32_32x32x16_bf16(kfr[ks], qfr[ks], sfT, 0, 0, 0);

      // wave-uniform gate: only diagonal tiles pay per-element masking
      bool tilemask = causal && (key0 + 31 > qwave0);
      unsigned pw[4][2];
#pragma unroll
      for (int g = 0; g < 4; ++g) {
        int kbase = key0 + 8 * g + 4 * half;
        float p[4];
#pragma unroll
        for (int r = 0; r < 4; ++r) {
          float s = sfT[g * 4 + r];
          if (tilemask && (kbase + r > qg)) s = -INFINITY;
          p[r] = exp2f(fminf(s, 43.f));
        }
        lsum += (p[0] + p[1]) + (p[2] + p[3]);
        pw[g][0] = pack2bf_fast(p[0], p[1]);
        pw[g][1] = pack2bf_fast(p[2], p[3]);
      }
      // cross-half quad exchange: C-layout -> A-operand layout, no LDS
#pragma unroll
      for (int m = 0; m < 2; ++m) {
        int owng = 2 * m + half, sendg = 2 * m + 1 - half;
        unsigned r0 = (unsigned)__shfl_xor((int)pw[sendg][0], 32, 64);
        unsigned r1 = (unsigned)__shfl_xor((int)pw[sendg][1], 32, 64);
        unsigned o0 = pw[owng][0], o1 = pw[owng][1];
        int4 fa = (half == 0) ? make_int4(o0, o1, r0, r1) : make_int4(r0, r1, o0, o1);
        bf16x8 ap = *(bf16x8*)&fa;
        int ks2 = kb * 2 + m;
        bf16x8 bv = *(const bf16x8*)(Vts + l31 * 72 + ks2 * 16 + half * 8);
        of = __builtin_amdgcn_mfma_f32_32x32x16_bf16(ap, bv, of, 0, 0, 0);
      }
    }
  }

  lsum += __shfl_xor(lsum, 32, 64);
  if (half == 0) Ls[wv * 32 + l31] = lsum;
  asm volatile("s_waitcnt lgkmcnt(0)" ::: "memory");
#pragma unroll
  for (int reg = 0; reg < 16; ++reg) {
    int ql = (reg & 3) + 8 * (reg >> 2) + 4 * half;
    int trow = qrow0 + wv * 32 + ql;
    float v = of[reg] * (wgt / Ls[wv * 32 + ql]);
    outbuf[(size_t)(b * TT + trow) * 512 + h * 32 + l31] = f2bf_fast(v);
  }
}

__global__ __launch_bounds__(256, 4) void flash_fused_kernel(
    const ushort* __restrict__ qbf,
    const ushort* __restrict__ kv,
    const ushort* __restrict__ krbf,
    const ushort* __restrict__ selt,
    const ushort* __restrict__ wint,
    const float* __restrict__ bw,
    ushort* __restrict__ att0, ushort* __restrict__ att1, ushort* __restrict__ att2) {
  __shared__ __align__(16) short VtsAll[2 * 32 * 72];
  __shared__ float Ls[128];
  int bx = blockIdx.x;
  int j = bx >> 5, bh = bx & 31;
  int b = bh >> 4, h = bh & 15;
  if (j < 32) {
    int qtile = (j < 16) ? (15 - (j >> 1)) : ((j - 16) >> 1);
    if ((j & 1) == 0) {  // cmp
      flash_src<32>(qbf, kv + h * 32, 1024, krbf, 64, kv + 512 + h * 32, 1024,
                    TT, 1, qtile, b, h, bw[b * 3 + 0], att0, VtsAll, Ls);
    } else {  // win
      flash_src<96>(qbf, wint + h * 96, 2048, wint, 2048, wint + 1536 + h * 32, 2048,
                    TT, 1, qtile, b, h, bw[b * 3 + 2], att2, VtsAll, Ls);
    }
  } else {  // sel
    int qtile = j - 32;
    flash_src<96>(qbf, selt + h * 96, 2048, selt, 2048, selt + 1536 + h * 32, 2048,
                  512, 0, qtile, b, h, bw[b * 3 + 1], att1, VtsAll, Ls);
  }
}

// ---------------- launch ----------------
extern "C" void kernel_launch(void* const* d_in, const int* in_sizes, int n_in,
                              void* d_out, int out_size, void* d_ws, size_t ws_size,
                              hipStream_t stream) {
  const float* x      = (const float*)d_in[0];
  const float* W_cq   = (const float*)d_in[1];
  const float* qnw    = (const float*)d_in[2];
  const float* W_dqn  = (const float*)d_in[3];
  const float* W_dqr  = (const float*)d_in[4];
  const float* W_ckv  = (const float*)d_in[5];
  const float* kvnw   = (const float*)d_in[6];
  const float* W_dkn  = (const float*)d_in[7];
  const float* W_dv   = (const float*)d_in[8];
  const float* W_kr   = (const float*)d_in[9];
  const float* W_imp  = (const float*)d_in[10];
  const float* b_imp  = (const float*)d_in[11];
  const float* W_selk = (const float*)d_in[12];
  const float* W_selv = (const float*)d_in[13];
  const float* W_wink = (const float*)d_in[14];
  const float* W_winv = (const float*)d_in[15];
  const float* W_gate = (const float*)d_in[16];
  const float* b_gate = (const float*)d_in[17];
  const float* W_proj = (const float*)d_in[18];
  const float* cos_f  = (const float*)d_in[19];
  const float* sin_f  = (const float*)d_in[20];
  float* out = (float*)d_out;
  float* ws  = (float*)d_ws;

  size_t off = 0;
  auto alloc = [&](size_t n) {
    float* p = ws + off;
    off += (n + 255) & ~(size_t)255;
    return p;
  };
  const int ROWS = 2 * TT;  // 4096
  ushort* xbf     = (ushort*)alloc((size_t)ROWS * 128);
  ushort* xhb     = (ushort*)alloc((size_t)ROWS * 128);
  float* nqraw    = alloc((size_t)ROWS * 128);
  float* nkvraw   = alloc((size_t)ROWS * 128);
  ushort* nqb     = (ushort*)alloc((size_t)ROWS * 48);
  ushort* qbf     = (ushort*)alloc((size_t)ROWS * 768);
  ushort* nkvb    = (ushort*)alloc((size_t)ROWS * 16);
  ushort* kvtmp   = (ushort*)alloc((size_t)ROWS * 512);
  ushort* krbf    = (ushort*)alloc((size_t)ROWS * 32);
  float* scores   = alloc(ROWS);
  float* bwp      = alloc(8);
  int* selidx     = (int*)alloc(1024);
  int* selflags   = (int*)alloc(ROWS);
  ushort* seltmp  = (ushort*)alloc((size_t)1024 * 1024);
  ushort* wintmp  = (ushort*)alloc((size_t)ROWS * 1024);
  ushort* att0    = (ushort*)alloc((size_t)ROWS * 256);
  ushort* att1    = (ushort*)alloc((size_t)ROWS * 256);
  ushort* att2    = (ushort*)alloc((size_t)ROWS * 256);
  ushort* Wt_q    = (ushort*)alloc((size_t)1536 * 48);
  ushort* Wt_kv   = (ushort*)alloc((size_t)1024 * 16);
  ushort* Wt_sel  = (ushort*)alloc((size_t)2048 * 128);
  ushort* Wt_win  = (ushort*)alloc((size_t)2048 * 128);
  ushort* Wt_proj = (ushort*)alloc((size_t)256 * 256);
  ushort* Wt_cq   = (ushort*)alloc((size_t)128 * 128);
  ushort* Wt_nkv  = (ushort*)alloc((size_t)128 * 128);

  wtconv_all_kernel<<<5568, 256, 0, stream>>>(
      W_dqn, W_dqr, W_dkn, W_dv, W_selk, W_selv, W_wink, W_winv, W_proj,
      W_cq, W_ckv, W_kr, W_gate, W_imp,
      Wt_q, Wt_kv, Wt_sel, Wt_win, Wt_proj, Wt_cq, Wt_nkv);

  logmap_kernel<<<ROWS, 256, 0, stream>>>(x, W_imp, b_imp, xhb, xbf, scores);

  gemm_kernel<<<dim3(32, 1, 2), 256, 0, stream>>>(
      0, xhb, Wt_cq, nqraw, xbf, Wt_nkv, nkvraw, nqb, Wt_q, qbf, nkvb, Wt_kv, kvtmp,
      Wt_win, wintmp, Wt_sel, seltmp, selidx, att0, att1, att2, Wt_proj, out, cos_f, sin_f);
  norm_kernel<<<2 * ROWS, 128, 0, stream>>>(nkvraw, nqraw, kvnw, qnw, cos_f, sin_f,
                                            nkvb, krbf, nqb);
  gemm_kernel<<<dim3(32, 20), 256, 0, stream>>>(
      1, xhb, Wt_cq, nqraw, xbf, Wt_nkv, nkvraw, nqb, Wt_q, qbf, nkvb, Wt_kv, kvtmp,
      Wt_win, wintmp, Wt_sel, seltmp, selidx, att0, att1, att2, Wt_proj, out, cos_f, sin_f);
  topk_rank_kernel<<<dim3(32, 2), 1024, 0, stream>>>(scores, selflags);
  topk_scan_kernel<<<2, 1024, 0, stream>>>(selflags, selidx, nkvraw, b_gate, bwp);
  gemm_kernel<<<dim3(40, 16), 256, 0, stream>>>(
      2, xhb, Wt_cq, nqraw, xbf, Wt_nkv, nkvraw, nqb, Wt_q, qbf, nkvb, Wt_kv, kvtmp,
      Wt_win, wintmp, Wt_sel, seltmp, selidx, att0, att1, att2, Wt_proj, out, cos_f, sin_f);

  flash_fused_kernel<<<1536, 256, 0, stream>>>(qbf, kvtmp, krbf, seltmp, wintmp, bwp,
                                               att0, att1, att2);

  gemm_kernel<<<dim3(32, 2), 256, 0, stream>>>(
      3, xhb, Wt_cq, nqraw, xbf, Wt_nkv, nkvraw, nqb, Wt_q, qbf, nkvb, Wt_kv, kvtmp,
      Wt_win, wintmp, Wt_sel, seltmp, selidx, att0, att1, att2, Wt_proj, out, cos_f, sin_f);
}

// Round 12
// 332.698 us; speedup vs baseline: 1.0592x; 1.0592x over previous
//
#include <hip/hip_runtime.h>
#include <hip/hip_bf16.h>
#include <math.h>

#define TT 2048
#define NE 256
#define NHEAD 16

typedef __attribute__((ext_vector_type(8))) short bf16x8;
typedef __attribute__((ext_vector_type(4))) float f32x4;
typedef __attribute__((ext_vector_type(16))) float f32x16;
typedef unsigned short ushort;
typedef __attribute__((ext_vector_type(8))) unsigned short us8;

__device__ __forceinline__ short f2bf(float x) {  // RNE (weights only)
  __hip_bfloat16 h = __float2bfloat16(x);
  return *reinterpret_cast<short*>(&h);
}
__device__ __forceinline__ ushort f2bf_fast(float x) {  // round-half-up
  return (ushort)((__float_as_uint(x) + 0x8000u) >> 16);
}
__device__ __forceinline__ unsigned pack2bf_fast(float a, float b) {
  unsigned ua = __float_as_uint(a) + 0x8000u;
  unsigned ub = __float_as_uint(b) + 0x8000u;
  return __builtin_amdgcn_perm(ub, ua, 0x07060302u);
}
__device__ __forceinline__ float bf2f(ushort u) {
  unsigned v = ((unsigned)u) << 16;
  return __uint_as_float(v);
}

// ---------------- front: logmap (blocks 0..4095) + weight convert (rest) ----------------
__global__ __launch_bounds__(256) void front_kernel(
    const float* __restrict__ x, const float* __restrict__ W_imp,
    const float* __restrict__ b_imp,
    ushort* __restrict__ xhb, ushort* __restrict__ xbf, float* __restrict__ scores,
    const float* __restrict__ W_dqn, const float* __restrict__ W_dqr,
    const float* __restrict__ W_dkn, const float* __restrict__ W_dv,
    const float* __restrict__ W_selk, const float* __restrict__ W_selv,
    const float* __restrict__ W_wink, const float* __restrict__ W_winv,
    const float* __restrict__ W_proj, const float* __restrict__ W_cq,
    const float* __restrict__ W_ckv, const float* __restrict__ W_kr,
    const float* __restrict__ W_gate,
    ushort* __restrict__ Wt_q, ushort* __restrict__ Wt_kv,
    ushort* __restrict__ Wt_sel, ushort* __restrict__ Wt_win,
    ushort* __restrict__ Wt_proj, ushort* __restrict__ Wt_cq,
    ushort* __restrict__ Wt_nkv) {
  __shared__ float red[20];
  int tid = threadIdx.x;
  if (blockIdx.x < 4096) {
    int row = blockIdx.x;
    int t = row & (TT - 1);
    float uv = x[row * NE + tid];
    float rv = (t == 0) ? 0.f : x[row * NE - NE + tid];
    xbf[row * NE + tid] = f2bf_fast(uv);
    float a = rv * rv, bq = uv * uv, c2 = -rv * uv, d4 = uv * W_imp[tid];
#pragma unroll
    for (int off = 32; off > 0; off >>= 1) {
      a += __shfl_down(a, off, 64);
      bq += __shfl_down(bq, off, 64);
      c2 += __shfl_down(c2, off, 64);
      d4 += __shfl_down(d4, off, 64);
    }
    if ((tid & 63) == 0) {
      int w = tid >> 6;
      red[w] = a; red[4 + w] = bq; red[8 + w] = c2; red[16 + w] = d4;
    }
    __syncthreads();
    float xn2 = red[0] + red[1] + red[2] + red[3];
    float un2 = red[4] + red[5] + red[6] + red[7];
    float ip  = red[8] + red[9] + red[10] + red[11];
    if (tid == 0) scores[row] = red[16] + red[17] + red[18] + red[19] + b_imp[0];
    float den = 1.f + 2.f * ip + xn2 * un2;
    float mob = ((1.f + 2.f * ip + un2) * (-rv) + (1.f - xn2) * uv) / den;
    float m2 = mob * mob;
#pragma unroll
    for (int off = 32; off > 0; off >>= 1) m2 += __shfl_down(m2, off, 64);
    if ((tid & 63) == 0) red[12 + (tid >> 6)] = m2;
    __syncthreads();
    float an2 = red[12] + red[13] + red[14] + red[15];
    float an = sqrtf(an2);
    float cf = 1.f + xn2;
    float arg = fminf(sqrtf(an), 0.999f);
    xhb[row * NE + tid] = f2bf_fast(cf * atanhf(arg) * mob / an);
    return;
  }
  int i = (blockIdx.x - 4096) * 256 + tid;
  // 1/sqrt(96) * log2(e): scores in log2 domain -> exp2 softmax
  const float scale = 0.14724456f;
  if (i < 147456) {  // Wt_q [1536 n][96 k]
    int k = i / 1536, n = i - k * 1536;
    float v = (n < 512) ? W_dqn[(size_t)k * 512 + n] : W_dqr[(size_t)k * 1024 + (n - 512)];
    Wt_q[(size_t)n * 96 + k] = (ushort)f2bf(v * scale);
  } else if (i < 180224) {  // Wt_kv [1024 n][32 k]
    int j = i - 147456;
    int k = j >> 10, n = j & 1023;
    float v = (n < 512) ? W_dkn[(size_t)k * 512 + n] : W_dv[(size_t)k * 512 + (n - 512)];
    Wt_kv[(size_t)n * 32 + k] = (ushort)f2bf(v);
  } else if (i < 704512) {  // Wt_sel [2048 n][256 k]
    int j = i - 180224;
    int k = j >> 11, n = j & 2047;
    float v = (n < 1536) ? W_selk[(size_t)k * 1536 + n] : W_selv[(size_t)k * 512 + (n - 1536)];
    Wt_sel[(size_t)n * 256 + k] = (ushort)f2bf(v);
  } else if (i < 1228800) {  // Wt_win [2048 n][256 k]
    int j = i - 704512;
    int k = j >> 11, n = j & 2047;
    float v = (n < 1536) ? W_wink[(size_t)k * 1536 + n] : W_winv[(size_t)k * 512 + (n - 1536)];
    Wt_win[(size_t)n * 256 + k] = (ushort)f2bf(v);
  } else if (i < 1359872) {  // Wt_proj [256 n][512 k]
    int j = i - 1228800;
    int k = j >> 8, n = j & 255;
    Wt_proj[(size_t)n * 512 + k] = (ushort)f2bf(W_proj[(size_t)k * 256 + n]);
  } else if (i < 1392640) {  // Wt_cq [128 n][256 k]
    int j = i - 1359872;
    int k = j >> 7, n = j & 127;
    float v = (n < 96) ? W_cq[(size_t)k * 96 + n] : 0.f;
    Wt_cq[(size_t)n * 256 + k] = (ushort)f2bf(v);
  } else if (i < 1425408) {  // Wt_nkv [128 n][256 k]: [ckv32|kr64|gate3|pad]
    int j = i - 1392640;
    int k = j >> 7, n = j & 127;
    float v;
    if (n < 32) v = W_ckv[(size_t)k * 32 + n];
    else if (n < 96) v = W_kr[(size_t)k * 64 + (n - 32)];
    else if (n < 99) v = W_gate[(size_t)k * 3 + (n - 96)];
    else v = 0.f;
    Wt_nkv[(size_t)n * 256 + k] = (ushort)f2bf(v);
  }
}

// ---------------- multi-mode bf16 MFMA GEMM ----------------
__global__ __launch_bounds__(256) void gemm_kernel(
    int mode,
    const ushort* __restrict__ xhb, const ushort* __restrict__ Wt_cq, float* __restrict__ nqraw,
    const ushort* __restrict__ xbf, const ushort* __restrict__ Wt_nkv, float* __restrict__ nkvraw,
    const ushort* __restrict__ nqb, const ushort* __restrict__ Wt_q, ushort* __restrict__ qbf,
    const ushort* __restrict__ nkvb, const ushort* __restrict__ Wt_kv, ushort* __restrict__ kvtmp,
    const ushort* __restrict__ Wt_win, ushort* __restrict__ wintmp,
    const ushort* __restrict__ Wt_sel, ushort* __restrict__ seltmp,
    const int* __restrict__ selidx,
    const ushort* __restrict__ att0, const ushort* __restrict__ att1,
    const ushort* __restrict__ att2, const ushort* __restrict__ Wt_proj,
    float* __restrict__ outF,
    const float* __restrict__ cosp, const float* __restrict__ sinp) {
  __shared__ __align__(16) short As[128 * 40];
  __shared__ __align__(16) short Bs[128 * 40];
  int tid = threadIdx.x;
  int wv = tid >> 6, lane = tid & 63;
  int l15 = lane & 15, quad = lane >> 4;
  int wm = wv >> 1, wn = wv & 1;

  const ushort* A = nullptr;
  const ushort* Bt = nullptr;
  void* Out = nullptr;
  int K, ldo, obf16 = 1, rope = 0, gather = 0, sum3 = 0;
  int m0 = blockIdx.x * 128, n0 = blockIdx.y * 128;
  if (mode == 0) {
    K = 256;
    if (blockIdx.y < 16) { A = xbf; Bt = Wt_win; Out = wintmp; ldo = 2048; }
    else if (blockIdx.y == 16) { A = xhb; Bt = Wt_cq; Out = nqraw; ldo = 128; obf16 = 0; n0 = 0; }
    else { A = xbf; Bt = Wt_nkv; Out = nkvraw; ldo = 128; obf16 = 0; n0 = 0; }
  } else if (mode == 1) {
    if (blockIdx.x < 32) {
      if (blockIdx.y < 12) {
        A = nqb; Bt = Wt_q; Out = qbf; K = 96; ldo = 1536;
        rope = (blockIdx.y >= 4);
      } else {
        A = nkvb; Bt = Wt_kv; Out = kvtmp; K = 32; ldo = 1024;
        n0 = (blockIdx.y - 12) * 128;
      }
    } else {
      if (blockIdx.y >= 16) return;
      A = xbf; Bt = Wt_sel; Out = seltmp; K = 256; ldo = 2048;
      gather = 1; m0 = (blockIdx.x - 32) * 128;
    }
  } else {
    K = 512; ldo = 256; obf16 = 0; sum3 = 1; Bt = Wt_proj; Out = outF;
  }

  int r = tid >> 1, seg = tid & 1;
  int arow = m0 + r;
  if (gather) arow = ((arow >> 9) * TT) + selidx[m0 + r];
  const ushort* ga = A + (size_t)arow * K + seg * 16;
  const ushort* gb = Bt + (size_t)(n0 + r) * K + seg * 16;

  auto loadA = [&](int kk, us8& a0, us8& a1) {
    if (sum3) {
      size_t base = (size_t)arow * 512 + seg * 16 + kk * 32;
      us8 p0 = *(const us8*)(att0 + base), p1 = *(const us8*)(att0 + base + 8);
      us8 q0 = *(const us8*)(att1 + base), q1 = *(const us8*)(att1 + base + 8);
      us8 r0 = *(const us8*)(att2 + base), r1 = *(const us8*)(att2 + base + 8);
#pragma unroll
      for (int e = 0; e < 8; ++e) {
        a0[e] = f2bf_fast(bf2f(p0[e]) + bf2f(q0[e]) + bf2f(r0[e]));
        a1[e] = f2bf_fast(bf2f(p1[e]) + bf2f(q1[e]) + bf2f(r1[e]));
      }
    } else {
      a0 = *(const us8*)(ga + kk * 32);
      a1 = *(const us8*)(ga + kk * 32 + 8);
    }
  };

  f32x4 acc[4][4];
#pragma unroll
  for (int i = 0; i < 4; ++i)
#pragma unroll
    for (int j = 0; j < 4; ++j) acc[i][j] = (f32x4){0.f, 0.f, 0.f, 0.f};

  int nk = K >> 5;
  us8 apre0, apre1, bpre0, bpre1;
  loadA(0, apre0, apre1);
  bpre0 = *(const us8*)gb;
  bpre1 = *(const us8*)(gb + 8);
  for (int kk = 0; kk < nk; ++kk) {
    __syncthreads();
    *(us8*)(As + r * 40 + seg * 16) = apre0;
    *(us8*)(As + r * 40 + seg * 16 + 8) = apre1;
    *(us8*)(Bs + r * 40 + seg * 16) = bpre0;
    *(us8*)(Bs + r * 40 + seg * 16 + 8) = bpre1;
    __syncthreads();
    if (kk + 1 < nk) {
      loadA(kk + 1, apre0, apre1);
      bpre0 = *(const us8*)(gb + (kk + 1) * 32);
      bpre1 = *(const us8*)(gb + (kk + 1) * 32 + 8);
    }
    bf16x8 af[4], bf[4];
#pragma unroll
    for (int mf = 0; mf < 4; ++mf)
      af[mf] = *(const bf16x8*)(As + (wm * 64 + mf * 16 + l15) * 40 + quad * 8);
#pragma unroll
    for (int nf = 0; nf < 4; ++nf)
      bf[nf] = *(const bf16x8*)(Bs + (wn * 64 + nf * 16 + l15) * 40 + quad * 8);
#pragma unroll
    for (int mf = 0; mf < 4; ++mf)
#pragma unroll
      for (int nf = 0; nf < 4; ++nf)
        acc[mf][nf] = __builtin_amdgcn_mfma_f32_16x16x32_bf16(af[mf], bf[nf], acc[mf][nf], 0, 0, 0);
  }

  if (rope) {
#pragma unroll
    for (int mf = 0; mf < 4; ++mf) {
#pragma unroll
      for (int nf = 0; nf < 2; ++nf) {
        int dd = nf * 16 + l15;
#pragma unroll
        for (int reg = 0; reg < 4; ++reg) {
          int row = m0 + wm * 64 + mf * 16 + quad * 4 + reg;
          int t = row & (TT - 1);
          float c = cosp[t * 32 + dd], s = sinp[t * 32 + dd];
          float xr = acc[mf][nf][reg], xi = acc[mf][nf + 2][reg];
          int col = n0 + wn * 64 + nf * 16 + l15;
          size_t oi = (size_t)row * ldo + col;
          ((ushort*)Out)[oi] = f2bf_fast(xr * c - xi * s);
          ((ushort*)Out)[oi + 32] = f2bf_fast(xr * s + xi * c);
        }
      }
    }
    return;
  }
#pragma unroll
  for (int mf = 0; mf < 4; ++mf) {
#pragma unroll
    for (int nf = 0; nf < 4; ++nf) {
#pragma unroll
      for (int reg = 0; reg < 4; ++reg) {
        int row = m0 + wm * 64 + mf * 16 + quad * 4 + reg;
        int col = n0 + wn * 64 + nf * 16 + l15;
        size_t oi = (size_t)row * ldo + col;
        float v = acc[mf][nf][reg];
        if (obf16) ((ushort*)Out)[oi] = f2bf_fast(v);
        else ((float*)Out)[oi] = v;
      }
    }
  }
}

// ---------------- merged norm/postproc ----------------
__global__ __launch_bounds__(128) void norm_kernel(const float* __restrict__ nkvraw,
                                                   const float* __restrict__ nqraw,
                                                   const float* __restrict__ kvnw,
                                                   const float* __restrict__ qnw,
                                                   const float* __restrict__ cos_t,
                                                   const float* __restrict__ sin_t,
                                                   ushort* __restrict__ nkvb,
                                                   ushort* __restrict__ krbf,
                                                   ushort* __restrict__ nqb) {
  int tid = threadIdx.x;
  if (blockIdx.x < 4096) {
    int row = blockIdx.x;
    int t = row & (TT - 1);
    if (tid < 32) {
      float v = nkvraw[(size_t)row * 128 + tid];
      float ss = v * v;
#pragma unroll
      for (int off = 16; off > 0; off >>= 1) ss += __shfl_xor(ss, off, 32);
      nkvb[(size_t)row * 32 + tid] = f2bf_fast(v * rsqrtf(ss / 32.f + 1e-6f) * kvnw[tid]);
    } else if (tid < 64) {
      int dd = tid - 32;
      float xr = nkvraw[(size_t)row * 128 + 32 + dd];
      float xi = nkvraw[(size_t)row * 128 + 64 + dd];
      float c = cos_t[t * 32 + dd], s = sin_t[t * 32 + dd];
      krbf[(size_t)row * 64 + dd] = f2bf_fast(xr * c - xi * s);
      krbf[(size_t)row * 64 + dd + 32] = f2bf_fast(xr * s + xi * c);
    }
  } else {
    int row = blockIdx.x - 4096;
    __shared__ float red2[2];
    float v = (tid < 96) ? nqraw[(size_t)row * 128 + tid] : 0.f;
    float p = v * v;
#pragma unroll
    for (int off = 32; off > 0; off >>= 1) p += __shfl_down(p, off, 64);
    if ((tid & 63) == 0) red2[tid >> 6] = p;
    __syncthreads();
    float ss = red2[0] + red2[1];
    float sc = rsqrtf(ss / 96.f + 1e-6f);
    if (tid < 96) nqb[(size_t)row * 96 + tid] = f2bf_fast(v * sc * qnw[tid]);
  }
}

// ---------------- top-k stage 1: ranks -> flags ----------------
__global__ __launch_bounds__(1024) void topk_rank_kernel(const float* __restrict__ scores,
                                                         int* __restrict__ flags) {
  int b = blockIdx.y, blk = blockIdx.x;
  int tid = threadIdx.x;
  __shared__ unsigned sk[TT];
#pragma unroll
  for (int e = 0; e < 2; ++e) {
    int i = tid + e * 1024;
    float s = scores[b * TT + i];
    unsigned u = __float_as_uint(s);
    u = (u & 0x80000000u) ? ~u : (u | 0x80000000u);
    sk[i] = u;
  }
  __syncthreads();
  int e = blk * 64 + (tid >> 4);
  int sub = tid & 15;
  unsigned u = sk[e];
  int r = 0;
  int j0 = sub * 128;
#pragma unroll 8
  for (int j = j0; j < j0 + 128; ++j) {
    unsigned v = sk[j];
    r += (int)((v > u) || (v == u && j < e));
  }
#pragma unroll
  for (int off = 8; off > 0; off >>= 1) r += __shfl_down(r, off, 16);
  if (sub == 0) flags[b * TT + e] = (r < 512) ? 1 : 0;
}

// ---------------- top-k stage 2: scan + scatter + gate finalize ----------------
__global__ __launch_bounds__(1024) void topk_scan_kernel(const int* __restrict__ flags,
                                                         int* __restrict__ selidx,
                                                         const float* __restrict__ nkvraw,
                                                         const float* __restrict__ b_gate,
                                                         float* __restrict__ bw) {
  int b = blockIdx.x, tid = threadIdx.x;
  __shared__ int pre[TT];
  __shared__ float gred[3][16];
  int f0 = flags[b * TT + tid], f1 = flags[b * TT + tid + 1024];
  pre[tid] = f0;
  pre[tid + 1024] = f1;
  __syncthreads();
  for (int off = 1; off < TT; off <<= 1) {
    int a0 = (tid >= off) ? pre[tid - off] : 0;
    int a1 = (tid + 1024 >= off) ? pre[tid + 1024 - off] : 0;
    __syncthreads();
    pre[tid] += a0;
    pre[tid + 1024] += a1;
    __syncthreads();
  }
  if (f0) selidx[b * 512 + pre[tid] - 1] = tid;
  if (f1) selidx[b * 512 + pre[tid + 1024] - 1] = tid + 1024;
  float g0 = 0, g1 = 0, g2 = 0;
  for (int r = tid; r < TT; r += 1024) {
    const float* p = nkvraw + (size_t)(b * TT + r) * 128 + 96;
    g0 += p[0]; g1 += p[1]; g2 += p[2];
  }
#pragma unroll
  for (int off = 32; off > 0; off >>= 1) {
    g0 += __shfl_down(g0, off, 64);
    g1 += __shfl_down(g1, off, 64);
    g2 += __shfl_down(g2, off, 64);
  }
  if ((tid & 63) == 0) {
    int w = tid >> 6;
    gred[0][w] = g0; gred[1][w] = g1; gred[2][w] = g2;
  }
  __syncthreads();
  if (tid == 0) {
    float v[3], mx = -INFINITY;
    for (int j = 0; j < 3; ++j) {
      float s = 0;
      for (int w = 0; w < 16; ++w) s += gred[j][w];
      v[j] = s / (float)TT + b_gate[j];
      mx = fmaxf(mx, v[j]);
    }
    float sum = 0.f;
    for (int j = 0; j < 3; ++j) { v[j] = expf(v[j] - mx); sum += v[j]; }
    for (int j = 0; j < 3; ++j) bw[b * 3 + j] = v[j] / sum;
  }
}

// ---------------- flash attention: compile-time strides, register Q/K, shuffle-P ----------------
// Scores in log2 domain (scale folded into Wt_q) -> exp2 softmax.
// (ks*16 < SPLIT) fully determines kb1 vs kb2 (half*8 <= 8 < 16), so strides
// are compile-time per ks -> strength-reduced induction adds.
template <int SPLIT, int KRS1, int KRS2, int VRS>
__device__ __forceinline__ void flash_src(
    const ushort* __restrict__ qbf, const ushort* __restrict__ kb1,
    const ushort* __restrict__ kb2, const ushort* __restrict__ vb,
    int Tk, int causal, int qtile, int b, int h, float wgt,
    ushort* __restrict__ outbuf, short* VtsAll, float* Ls) {
  int tid = threadIdx.x;
  int wv = tid >> 6, lane = tid & 63;
  int l31 = lane & 31, half = lane >> 5;
  int qrow0 = qtile * 128;
  size_t bTk = (size_t)b * Tk;

  // Q fragments in registers (reused across all K-tiles)
  bf16x8 qfr[6];
  {
    const ushort* qrow = qbf + (size_t)(b * TT + qrow0 + wv * 32 + l31) * 1536;
#pragma unroll
    for (int ks = 0; ks < 6; ++ks) {
      int dp = ks * 16 + half * 8;
      int col = (dp < 32) ? (h * 32 + dp) : (512 + h * 64 + (dp - 32));
      qfr[ks] = *(const bf16x8*)(qrow + col);
    }
  }
  // K base pointers (per-lane part hoisted); strides compile-time per ks
  const ushort* kptr[6];
#pragma unroll
  for (int ks = 0; ks < 6; ++ks) {
    int dp = ks * 16 + half * 8;
    kptr[ks] = (ks * 16 < SPLIT) ? kb1 + (bTk + l31) * KRS1 + dp
                                 : kb2 + (bTk + l31) * KRS2 + (dp - SPLIT);
  }
  const ushort* vptrA[2];
  const ushort* vptrB[2];
#pragma unroll
  for (int c = 0; c < 2; ++c) {
    int i = c * 256 + tid;
    int d0 = (i & 15) * 2, kjp = (i >> 4) * 2;
    vptrA[c] = vb + (bTk + kjp) * VRS + d0;
    vptrB[c] = vptrA[c] + VRS;
  }

  f32x16 of;
#pragma unroll
  for (int r = 0; r < 16; ++r) of[r] = 0.f;
  float lsum = 0.f;

  ushort2 va0, va1, vb0, vb1;
  auto vprefetch = [&](int kt) {
    size_t o = (size_t)(kt * 64) * VRS;
    va0 = *(const ushort2*)(vptrA[0] + o);
    vb0 = *(const ushort2*)(vptrB[0] + o);
    va1 = *(const ushort2*)(vptrA[1] + o);
    vb1 = *(const ushort2*)(vptrB[1] + o);
  };

  int nkt = causal ? (2 * qtile + 2) : (Tk >> 6);
  int qg = qrow0 + wv * 32 + l31;
  int qwave0 = qrow0 + wv * 32;  // wave-uniform
  vprefetch(0);
  for (int kt = 0; kt < nkt; ++kt) {
    short* Vts = VtsAll + (kt & 1) * (32 * 72);
    {
      int i0 = tid, i1 = 256 + tid;
      int d0a = (i0 & 15) * 2, kj0 = (i0 >> 4) * 2;
      int d0b = (i1 & 15) * 2, kj1 = (i1 >> 4) * 2;
      unsigned a0 = *(unsigned*)&va0, b0 = *(unsigned*)&vb0;
      unsigned a1 = *(unsigned*)&va1, b1 = *(unsigned*)&vb1;
      // perm(src0,src1,sel): src1 supplies bytes 0-3, src0 bytes 4-7.
      // word d0+0 = [a.b0,a.b1,b.b0,b.b1] -> sel 0x05040100
      // word d0+1 = [a.b2,a.b3,b.b2,b.b3] -> sel 0x07060302
      *(unsigned*)(Vts + (d0a + 0) * 72 + kj0) = __builtin_amdgcn_perm(b0, a0, 0x05040100u);
      *(unsigned*)(Vts + (d0a + 1) * 72 + kj0) = __builtin_amdgcn_perm(b0, a0, 0x07060302u);
      *(unsigned*)(Vts + (d0b + 0) * 72 + kj1) = __builtin_amdgcn_perm(b1, a1, 0x05040100u);
      *(unsigned*)(Vts + (d0b + 1) * 72 + kj1) = __builtin_amdgcn_perm(b1, a1, 0x07060302u);
    }
    __syncthreads();
    if (kt + 1 < nkt) vprefetch(kt + 1);

#pragma unroll
    for (int kb = 0; kb < 2; ++kb) {
      int key0 = kt * 64 + kb * 32;
      bf16x8 kfr[6];
#pragma unroll
      for (int ks = 0; ks < 6; ++ks) {
        const int krs_ks = (ks * 16 < SPLIT) ? KRS1 : KRS2;
        kfr[ks] = *(const bf16x8*)(kptr[ks] + (size_t)key0 * krs_ks);
      }
      f32x16 sfT;
#pragma unroll
      for (int r = 0; r < 16; ++r) sfT[r] = 0.f;
#pragma unroll
      for (int ks = 0; ks < 6; ++ks)
        sfT = __builtin_amdgcn_mfma_f32_32x32x16_bf16(kfr[ks], qfr[ks], sfT, 0, 0, 0);

      bool tilemask = causal && (key0 + 31 > qwave0);
      unsigned pw[4][2];
#pragma unroll
      for (int g = 0; g < 4; ++g) {
        int kbase = key0 + 8 * g + 4 * half;
        float p[4];
#pragma unroll
        for (int r = 0; r < 4; ++r) {
          float s = sfT[g * 4 + r];
          if (tilemask && (kbase + r > qg)) s = -INFINITY;
          p[r] = __builtin_amdgcn_exp2f(fminf(s, 43.f));
        }
        lsum += (p[0] + p[1]) + (p[2] + p[3]);
        pw[g][0] = pack2bf_fast(p[0], p[1]);
        pw[g][1] = pack2bf_fast(p[2], p[3]);
      }
      // cross-half quad exchange: C-layout -> A-operand layout, no LDS
#pragma unroll
      for (int m = 0; m < 2; ++m) {
        int owng = 2 * m + half, sendg = 2 * m + 1 - half;
        unsigned r0 = (unsigned)__shfl_xor((int)pw[sendg][0], 32, 64);
        unsigned r1 = (unsigned)__shfl_xor((int)pw[sendg][1], 32, 64);
        unsigned o0 = pw[owng][0], o1 = pw[owng][1];
        int4 fa = (half == 0) ? make_int4(o0, o1, r0, r1) : make_int4(r0, r1, o0, o1);
        bf16x8 ap = *(bf16x8*)&fa;
        int ks2 = kb * 2 + m;
        bf16x8 bv = *(const bf16x8*)(Vts + l31 * 72 + ks2 * 16 + half * 8);
        of = __builtin_amdgcn_mfma_f32_32x32x16_bf16(ap, bv, of, 0, 0, 0);
      }
    }
  }

  lsum += __shfl_xor(lsum, 32, 64);
  if (half == 0) Ls[wv * 32 + l31] = lsum;
  asm volatile("s_waitcnt lgkmcnt(0)" ::: "memory");
#pragma unroll
  for (int reg = 0; reg < 16; ++reg) {
    int ql = (reg & 3) + 8 * (reg >> 2) + 4 * half;
    int trow = qrow0 + wv * 32 + ql;
    float v = of[reg] * (wgt / Ls[wv * 32 + ql]);
    outbuf[(size_t)(b * TT + trow) * 512 + h * 32 + l31] = f2bf_fast(v);
  }
}

__global__ __launch_bounds__(256, 3) void flash_fused_kernel(
    const ushort* __restrict__ qbf,
    const ushort* __restrict__ kv,
    const ushort* __restrict__ krbf,
    const ushort* __restrict__ selt,
    const ushort* __restrict__ wint,
    const float* __restrict__ bw,
    ushort* __restrict__ att0, ushort* __restrict__ att1, ushort* __restrict__ att2) {
  __shared__ __align__(16) short VtsAll[2 * 32 * 72];
  __shared__ float Ls[128];
  int bx = blockIdx.x;
  int j = bx >> 5, bh = bx & 31;
  int b = bh >> 4, h = bh & 15;
  if (j < 32) {
    int qtile = (j < 16) ? (15 - (j >> 1)) : ((j - 16) >> 1);
    if ((j & 1) == 0) {  // cmp
      flash_src<32, 1024, 64, 1024>(qbf, kv + h * 32, krbf, kv + 512 + h * 32,
                                    TT, 1, qtile, b, h, bw[b * 3 + 0], att0, VtsAll, Ls);
    } else {  // win
      flash_src<96, 2048, 2048, 2048>(qbf, wint + h * 96, wint, wint + 1536 + h * 32,
                                      TT, 1, qtile, b, h, bw[b * 3 + 2], att2, VtsAll, Ls);
    }
  } else {  // sel
    int qtile = j - 32;
    flash_src<96, 2048, 2048, 2048>(qbf, selt + h * 96, selt, selt + 1536 + h * 32,
                                    512, 0, qtile, b, h, bw[b * 3 + 1], att1, VtsAll, Ls);
  }
}

// ---------------- launch ----------------
extern "C" void kernel_launch(void* const* d_in, const int* in_sizes, int n_in,
                              void* d_out, int out_size, void* d_ws, size_t ws_size,
                              hipStream_t stream) {
  const float* x      = (const float*)d_in[0];
  const float* W_cq   = (const float*)d_in[1];
  const float* qnw    = (const float*)d_in[2];
  const float* W_dqn  = (const float*)d_in[3];
  const float* W_dqr  = (const float*)d_in[4];
  const float* W_ckv  = (const float*)d_in[5];
  const float* kvnw   = (const float*)d_in[6];
  const float* W_dkn  = (const float*)d_in[7];
  const float* W_dv   = (const float*)d_in[8];
  const float* W_kr   = (const float*)d_in[9];
  const float* W_imp  = (const float*)d_in[10];
  const float* b_imp  = (const float*)d_in[11];
  const float* W_selk = (const float*)d_in[12];
  const float* W_selv = (const float*)d_in[13];
  const float* W_wink = (const float*)d_in[14];
  const float* W_winv = (const float*)d_in[15];
  const float* W_gate = (const float*)d_in[16];
  const float* b_gate = (const float*)d_in[17];
  const float* W_proj = (const float*)d_in[18];
  const float* cos_f  = (const float*)d_in[19];
  const float* sin_f  = (const float*)d_in[20];
  float* out = (float*)d_out;
  float* ws  = (float*)d_ws;

  size_t off = 0;
  auto alloc = [&](size_t n) {
    float* p = ws + off;
    off += (n + 255) & ~(size_t)255;
    return p;
  };
  const int ROWS = 2 * TT;  // 4096
  ushort* xbf     = (ushort*)alloc((size_t)ROWS * 128);
  ushort* xhb     = (ushort*)alloc((size_t)ROWS * 128);
  float* nqraw    = alloc((size_t)ROWS * 128);
  float* nkvraw   = alloc((size_t)ROWS * 128);
  ushort* nqb     = (ushort*)alloc((size_t)ROWS * 48);
  ushort* qbf     = (ushort*)alloc((size_t)ROWS * 768);
  ushort* nkvb    = (ushort*)alloc((size_t)ROWS * 16);
  ushort* kvtmp   = (ushort*)alloc((size_t)ROWS * 512);
  ushort* krbf    = (ushort*)alloc((size_t)ROWS * 32);
  float* scores   = alloc(ROWS);
  float* bwp      = alloc(8);
  int* selidx     = (int*)alloc(1024);
  int* selflags   = (int*)alloc(ROWS);
  ushort* seltmp  = (ushort*)alloc((size_t)1024 * 1024);
  ushort* wintmp  = (ushort*)alloc((size_t)ROWS * 1024);
  ushort* att0    = (ushort*)alloc((size_t)ROWS * 256);
  ushort* att1    = (ushort*)alloc((size_t)ROWS * 256);
  ushort* att2    = (ushort*)alloc((size_t)ROWS * 256);
  ushort* Wt_q    = (ushort*)alloc((size_t)1536 * 48);
  ushort* Wt_kv   = (ushort*)alloc((size_t)1024 * 16);
  ushort* Wt_sel  = (ushort*)alloc((size_t)2048 * 128);
  ushort* Wt_win  = (ushort*)alloc((size_t)2048 * 128);
  ushort* Wt_proj = (ushort*)alloc((size_t)256 * 256);
  ushort* Wt_cq   = (ushort*)alloc((size_t)128 * 128);
  ushort* Wt_nkv  = (ushort*)alloc((size_t)128 * 128);

  front_kernel<<<4096 + 5568, 256, 0, stream>>>(
      x, W_imp, b_imp, xhb, xbf, scores,
      W_dqn, W_dqr, W_dkn, W_dv, W_selk, W_selv, W_wink, W_winv, W_proj,
      W_cq, W_ckv, W_kr, W_gate,
      Wt_q, Wt_kv, Wt_sel, Wt_win, Wt_proj, Wt_cq, Wt_nkv);

  topk_rank_kernel<<<dim3(32, 2), 1024, 0, stream>>>(scores, selflags);

  gemm_kernel<<<dim3(32, 18), 256, 0, stream>>>(
      0, xhb, Wt_cq, nqraw, xbf, Wt_nkv, nkvraw, nqb, Wt_q, qbf, nkvb, Wt_kv, kvtmp,
      Wt_win, wintmp, Wt_sel, seltmp, selidx, att0, att1, att2, Wt_proj, out, cos_f, sin_f);

  norm_kernel<<<2 * ROWS, 128, 0, stream>>>(nkvraw, nqraw, kvnw, qnw, cos_f, sin_f,
                                            nkvb, krbf, nqb);
  topk_scan_kernel<<<2, 1024, 0, stream>>>(selflags, selidx, nkvraw, b_gate, bwp);

  gemm_kernel<<<dim3(40, 20), 256, 0, stream>>>(
      1, xhb, Wt_cq, nqraw, xbf, Wt_nkv, nkvraw, nqb, Wt_q, qbf, nkvb, Wt_kv, kvtmp,
      Wt_win, wintmp, Wt_sel, seltmp, selidx, att0, att1, att2, Wt_proj, out, cos_f, sin_f);

  flash_fused_kernel<<<1536, 256, 0, stream>>>(qbf, kvtmp, krbf, seltmp, wintmp, bwp,
                                               att0, att1, att2);

  gemm_kernel<<<dim3(32, 2), 256, 0, stream>>>(
      3, xhb, Wt_cq, nqraw, xbf, Wt_nkv, nkvraw, nqb, Wt_q, qbf, nkvb, Wt_kv, kvtmp,
      Wt_win, wintmp, Wt_sel, seltmp, selidx, att0, att1, att2, Wt_proj, out, cos_f, sin_f);
}